// Round 5
// baseline (422.245 us; speedup 1.0000x reference)
//
#include <hip/hip_runtime.h>
#include <hip/hip_bf16.h>

#define S_ 4
#define B_ 256
#define L_ 256
#define D_ 512
#define NQ_ 4
#define H_ 2048
#define G_ 3072

typedef __attribute__((ext_vector_type(4))) float f32x4;
typedef __attribute__((ext_vector_type(8))) short s16x8;

__device__ __forceinline__ unsigned short f2bf(float x) {
    __hip_bfloat16 hb = __float2bfloat16(x);
    return reinterpret_cast<unsigned short&>(hb);
}

// block-wide sum for 256-thread blocks; red is __shared__ float[8]
__device__ __forceinline__ float block_sum256(float v, float* red) {
    #pragma unroll
    for (int off = 32; off > 0; off >>= 1) v += __shfl_down(v, off, 64);
    int tid = threadIdx.x;
    int lane = tid & 63, wid = tid >> 6;
    if (lane == 0) red[wid] = v;
    __syncthreads();
    float r = (tid < 4) ? red[tid] : 0.f;
    #pragma unroll
    for (int off = 4; off > 0; off >>= 1) r += __shfl_down(r, off, 64);
    if (tid == 0) red[0] = r;
    __syncthreads();
    float out = red[0];
    __syncthreads();
    return out;
}

// ---------------- kernel 1: masked mean pool over L (r2 version, known-good) ----------------
__global__ __launch_bounds__(256) void pool_kernel(
    const float* __restrict__ seq_tokens,
    const unsigned char* __restrict__ masks_raw,
    float* __restrict__ pooled)                // (S,B,D)
{
    const int sb = blockIdx.x;
    const int tid = threadIdx.x;
    __shared__ float sval[L_];
    __shared__ float scount[4];
    __shared__ f32x4 spart[256];
    __shared__ int is_bool_flag;

    if (tid == 0) is_bool_flag = 0;
    __syncthreads();
    {
        unsigned int w = reinterpret_cast<const unsigned int*>(masks_raw)[tid];
        if (w & 0xFFFFFF00u) is_bool_flag = 1;   // benign race, same value
    }
    __syncthreads();
    const bool is_bool = (is_bool_flag != 0);

    int mval;
    if (is_bool) mval = masks_raw[(size_t)sb * L_ + tid];
    else         mval = reinterpret_cast<const int*>(masks_raw)[(size_t)sb * L_ + tid];
    float valid = mval ? 0.f : 1.f;
    sval[tid] = valid;
    float c = valid;
    #pragma unroll
    for (int off = 32; off > 0; off >>= 1) c += __shfl_down(c, off, 64);
    if ((tid & 63) == 0) scount[tid >> 6] = c;
    __syncthreads();
    const float denom = fmaxf(scount[0] + scount[1] + scount[2] + scount[3], 1.f);

    const float* base = seq_tokens + (size_t)sb * L_ * D_;
    const int cidx = tid & 127;
    const int rg = tid >> 7;
    f32x4 acc = {0.f, 0.f, 0.f, 0.f};
    for (int l = rg; l < L_; l += 2) {
        float vl = sval[l];
        f32x4 v = *reinterpret_cast<const f32x4*>(base + (size_t)l * D_ + cidx * 4);
        acc += v * vl;
    }
    spart[tid] = acc;
    __syncthreads();
    if (tid < 128) {
        f32x4 r = spart[tid] + spart[tid + 128];
        r *= (1.f / denom);
        *reinterpret_cast<f32x4*>(pooled + (size_t)sb * D_ + cidx * 4) = r;
    }
}

// ---------------- kernel 2: stat proj + LN, concat, group LN -> gi2 (bf16, MFMA-frag-tiled) ---
// gi2 layout: [s][kc=G/8][b=256][j=8]  so gemm1's A-fragment dwordx4 loads are 1 KB contiguous.
__global__ __launch_bounds__(256) void gi_kernel(
    const float* __restrict__ ns_tokens,    // (B, 2048)
    const float* __restrict__ seq_stats,    // (S,B,6)
    const float* __restrict__ stat_W,       // (S,6,D)
    const float* __restrict__ stat_b,       // (S,D)
    const float* __restrict__ stat_ln_g,
    const float* __restrict__ stat_ln_b,
    const float* __restrict__ gin_gamma,    // (G)
    const float* __restrict__ gin_beta,
    const float* __restrict__ pooled,       // (S,B,D)
    __hip_bfloat16* __restrict__ gi2)       // (S, 384, 256, 8)
{
    const int sb = blockIdx.x;
    const int s = sb >> 8;
    const int b = sb & 255;
    const int tid = threadIdx.x;
    __shared__ float red[8];
    __shared__ float sstat[D_];

    float st[6];
    #pragma unroll
    for (int f = 0; f < 6; ++f) st[f] = seq_stats[(size_t)sb * 6 + f];

    float sp[2];
    #pragma unroll
    for (int k = 0; k < 2; ++k) {
        int d = tid + k * 256;
        float a = stat_b[s * D_ + d];
        #pragma unroll
        for (int f = 0; f < 6; ++f) a += st[f] * stat_W[(s * 6 + f) * D_ + d];
        sp[k] = a;
    }
    float ssum = block_sum256(sp[0] + sp[1], red);
    float ssq  = block_sum256(sp[0] * sp[0] + sp[1] * sp[1], red);
    float mu = ssum / D_;
    float var = ssq / D_ - mu * mu;
    float rinv = rsqrtf(var + 1e-5f);
    #pragma unroll
    for (int k = 0; k < 2; ++k) {
        int d = tid + k * 256;
        sstat[d] = (sp[k] - mu) * rinv * stat_ln_g[s * D_ + d] + stat_ln_b[s * D_ + d];
    }
    __syncthreads();

    float gv[12];
    float gsum = 0.f, gsq = 0.f;
    #pragma unroll
    for (int k = 0; k < 12; ++k) {
        int g = tid + k * 256;
        float v;
        if (g < 2048)       v = ns_tokens[(size_t)b * 2048 + g];
        else if (g < 2560)  v = pooled[(size_t)sb * D_ + (g - 2048)];
        else                v = sstat[g - 2560];
        gv[k] = v;
        gsum += v;
        gsq += v * v;
    }
    gsum = block_sum256(gsum, red);
    gsq  = block_sum256(gsq, red);
    mu = gsum / G_;
    var = gsq / G_ - mu * mu;
    rinv = rsqrtf(var + 1e-5f);
    #pragma unroll
    for (int k = 0; k < 12; ++k) {
        int g = tid + k * 256;
        float o = (gv[k] - mu) * rinv * gin_gamma[g] + gin_beta[g];
        int kc = g >> 3, j = g & 7;
        gi2[((size_t)s * 384 + kc) * 2048 + b * 8 + j] = __float2bfloat16(o);
    }
}

// ---------------- kernel 3: GEMM1  h = silu(gi @ W1 + b1) -- barrier-free streaming ----------
// per (s,q): (256 x 3072) x (3072 x 2048). BM=256 (W1 read once), BN=32, grid 1024, 4 blk/CU.
// NO LDS, NO __syncthreads in the K-loop: every wave independently streams
//   A-frags (dwordx4, 1 KB contiguous from L2-resident gi2) and
//   W dwords (f32 from HBM, saddr-form, depth-2 register pipeline) straight into MFMA.
// The HBM pipe is never drained by a barrier; 16 waves/CU provide phase diversity (m114 TLP).
#define G1_STEP(KC, BC, BN) do {                                                     \
    s16x8 bw0, bw1;                                                                  \
    bw0[0]=(short)f2bf(BC[0]);  bw0[1]=(short)f2bf(BC[1]);                           \
    bw0[2]=(short)f2bf(BC[2]);  bw0[3]=(short)f2bf(BC[3]);                           \
    bw0[4]=(short)f2bf(BC[4]);  bw0[5]=(short)f2bf(BC[5]);                           \
    bw0[6]=(short)f2bf(BC[6]);  bw0[7]=(short)f2bf(BC[7]);                           \
    bw1[0]=(short)f2bf(BC[8]);  bw1[1]=(short)f2bf(BC[9]);                           \
    bw1[2]=(short)f2bf(BC[10]); bw1[3]=(short)f2bf(BC[11]);                          \
    bw1[4]=(short)f2bf(BC[12]); bw1[5]=(short)f2bf(BC[13]);                          \
    bw1[6]=(short)f2bf(BC[14]); bw1[7]=(short)f2bf(BC[15]);                          \
    unsigned avk = av0 + (unsigned)(KC) * 16384u;                                    \
    s16x8 a0 = *reinterpret_cast<const s16x8*>(AbU + avk);                           \
    s16x8 a1 = *reinterpret_cast<const s16x8*>(AbU + avk + 256);                     \
    s16x8 a2 = *reinterpret_cast<const s16x8*>(AbU + avk + 512);                     \
    s16x8 a3 = *reinterpret_cast<const s16x8*>(AbU + avk + 768);                     \
    int kn_ = (KC) + 1; if (kn_ > 95) kn_ = 95;                                      \
    unsigned vk = wv0 + (unsigned)kn_ * (32u * H_);                                  \
    BN[0] = Wj0[vk];      BN[1] = Wj1[vk];      BN[2] = Wj2[vk];                     \
    BN[3] = Wj3[vk];      BN[4] = Wj4[vk];      BN[5] = Wj5[vk];                     \
    BN[6] = Wj6[vk];      BN[7] = Wj7[vk];                                           \
    BN[8] = Wj0[vk + 16]; BN[9] = Wj1[vk + 16]; BN[10] = Wj2[vk + 16];               \
    BN[11] = Wj3[vk + 16]; BN[12] = Wj4[vk + 16]; BN[13] = Wj5[vk + 16];             \
    BN[14] = Wj6[vk + 16]; BN[15] = Wj7[vk + 16];                                    \
    acc[0][0] = __builtin_amdgcn_mfma_f32_16x16x32_bf16(a0, bw0, acc[0][0], 0, 0, 0);\
    acc[0][1] = __builtin_amdgcn_mfma_f32_16x16x32_bf16(a0, bw1, acc[0][1], 0, 0, 0);\
    acc[1][0] = __builtin_amdgcn_mfma_f32_16x16x32_bf16(a1, bw0, acc[1][0], 0, 0, 0);\
    acc[1][1] = __builtin_amdgcn_mfma_f32_16x16x32_bf16(a1, bw1, acc[1][1], 0, 0, 0);\
    acc[2][0] = __builtin_amdgcn_mfma_f32_16x16x32_bf16(a2, bw0, acc[2][0], 0, 0, 0);\
    acc[2][1] = __builtin_amdgcn_mfma_f32_16x16x32_bf16(a2, bw1, acc[2][1], 0, 0, 0);\
    acc[3][0] = __builtin_amdgcn_mfma_f32_16x16x32_bf16(a3, bw0, acc[3][0], 0, 0, 0);\
    acc[3][1] = __builtin_amdgcn_mfma_f32_16x16x32_bf16(a3, bw1, acc[3][1], 0, 0, 0);\
} while (0)

__global__ __launch_bounds__(256, 4) void gemm1_kernel(
    const __hip_bfloat16* __restrict__ gi2,   // (S, 384, 256, 8)
    const float* __restrict__ W1,
    const float* __restrict__ b1,
    __hip_bfloat16* __restrict__ hbuf)        // (S*Nq, B, H)
{
    // bijective XCD swizzle: 1024 blocks, 128/XCD -> each XCD owns 2 sq (one s) -> gi2 L2-local
    const int bid = blockIdx.x;
    const int wg = (bid & 7) * 128 + (bid >> 3);
    const int ntile = wg & 63;      // 0..63, 32-col tiles
    const int sq = wg >> 6;         // 0..15
    const int s = sq >> 2;
    const int tid = threadIdx.x;
    const int lane = tid & 63;
    const int wid = tid >> 6;       // wave owns m-rows wid*64..+63
    const int l15 = lane & 15;
    const int l4  = lane >> 4;      // k-chunk group

    // A: uniform base + 32-bit lane offset; frag mf at +mf*256 bytes (imm-foldable)
    const char* AbU = reinterpret_cast<const char*>(gi2) + (size_t)s * 1572864;  // 384*2048*2
    const unsigned av0 = (unsigned)((l4 * 256 + wid * 64 + l15) * 16);

    // W: 8 uniform row-bases (j*H) + one lane voffset; nf at +16 floats (imm-foldable)
    const float* Wsq = W1 + (size_t)sq * ((size_t)G_ * H_);
    const float* Wj0 = Wsq;           const float* Wj1 = Wsq + 1 * H_;
    const float* Wj2 = Wsq + 2 * H_;  const float* Wj3 = Wsq + 3 * H_;
    const float* Wj4 = Wsq + 4 * H_;  const float* Wj5 = Wsq + 5 * H_;
    const float* Wj6 = Wsq + 6 * H_;  const float* Wj7 = Wsq + 7 * H_;
    const unsigned wv0 = (unsigned)(l4 * 8 * H_ + ntile * 32 + l15);

    f32x4 acc[4][2];
    #pragma unroll
    for (int i = 0; i < 4; ++i)
        #pragma unroll
        for (int j = 0; j < 2; ++j) acc[i][j] = (f32x4){0.f, 0.f, 0.f, 0.f};

    float bufA[16], bufB[16];
    // prologue: W(kc=0) -> bufA
    {
        unsigned vk = wv0;
        bufA[0] = Wj0[vk];      bufA[1] = Wj1[vk];      bufA[2] = Wj2[vk];
        bufA[3] = Wj3[vk];      bufA[4] = Wj4[vk];      bufA[5] = Wj5[vk];
        bufA[6] = Wj6[vk];      bufA[7] = Wj7[vk];
        bufA[8] = Wj0[vk + 16]; bufA[9] = Wj1[vk + 16]; bufA[10] = Wj2[vk + 16];
        bufA[11] = Wj3[vk + 16]; bufA[12] = Wj4[vk + 16]; bufA[13] = Wj5[vk + 16];
        bufA[14] = Wj6[vk + 16]; bufA[15] = Wj7[vk + 16];
    }

    #pragma unroll 1
    for (int kc = 0; kc < 96; kc += 2) {
        G1_STEP(kc, bufA, bufB);
        G1_STEP(kc + 1, bufB, bufA);
    }

    // epilogue: + b1, silu, bf16 store (verified 16x16 C-layout: col=l15, row=l4*4+r)
    const float* b1p = b1 + (size_t)sq * H_ + ntile * 32;
    __hip_bfloat16* hp = hbuf + (size_t)sq * B_ * H_;
    #pragma unroll
    for (int mf = 0; mf < 4; ++mf)
        #pragma unroll
        for (int nf = 0; nf < 2; ++nf)
            #pragma unroll
            for (int r = 0; r < 4; ++r) {
                int row = wid * 64 + mf * 16 + l4 * 4 + r;
                int col = nf * 16 + l15;
                float x = acc[mf][nf][r] + b1p[col];
                float sg = 1.f / (1.f + __expf(-x));
                hp[(size_t)row * H_ + ntile * 32 + col] = __float2bfloat16(x * sg);
            }
}

// ---------------- kernel 4: GEMM2  qpre = h @ W2 (bf16 out) ----------------
__global__ __launch_bounds__(256) void gemm2_kernel(
    const __hip_bfloat16* __restrict__ hbuf,
    const float* __restrict__ W2,
    __hip_bfloat16* __restrict__ qpre)      // (S*Nq, B, D)
{
    const int ntile = blockIdx.x;   // 0..7
    const int mtile = blockIdx.y;   // 0..1
    const int sq = blockIdx.z;      // 0..15
    const int tid = threadIdx.x;
    const int lane = tid & 63;
    const int wid = tid >> 6;
    const int wm = wid >> 1, wn = wid & 1;

    __shared__ __align__(16) unsigned short As[128 * 64];
    __shared__ __align__(16) unsigned short Ws[64 * 64];

    const __hip_bfloat16* Ab = hbuf + ((size_t)sq * B_ + mtile * 128) * H_;
    const float* Wb = W2 + (size_t)sq * H_ * D_ + ntile * 64;

    f32x4 acc[4][2];
    #pragma unroll
    for (int i = 0; i < 4; ++i)
        #pragma unroll
        for (int j = 0; j < 2; ++j) acc[i][j] = (f32x4){0.f, 0.f, 0.f, 0.f};

    const int wn0 = (tid & 15) * 4;
    const int wk0 = (tid >> 4) * 4;

    for (int kt = 0; kt < H_ / 64; ++kt) {
        const int kbase = kt * 64;
        __syncthreads();
        #pragma unroll
        for (int i = 0; i < 4; ++i) {
            int slot = i * 256 + tid;
            int row = slot >> 3, cc = slot & 7;
            int swz = (row ^ (row >> 3)) & 7;
            s16x8 v = *reinterpret_cast<const s16x8*>(Ab + (size_t)row * H_ + kbase + cc * 8);
            *reinterpret_cast<s16x8*>(&As[row * 64 + ((cc ^ swz) * 8)]) = v;
        }
        float wv[4][4];
        #pragma unroll
        for (int kk = 0; kk < 4; ++kk) {
            f32x4 t = *reinterpret_cast<const f32x4*>(Wb + (size_t)(kbase + wk0 + kk) * D_ + wn0);
            #pragma unroll
            for (int j = 0; j < 4; ++j) wv[kk][j] = t[j];
        }
        #pragma unroll
        for (int nn = 0; nn < 4; ++nn) {
            int row = wn0 + nn;
            int swz = (row ^ (row >> 3)) & 7;
            unsigned long long pk =
                (unsigned long long)f2bf(wv[0][nn]) |
                ((unsigned long long)f2bf(wv[1][nn]) << 16) |
                ((unsigned long long)f2bf(wv[2][nn]) << 32) |
                ((unsigned long long)f2bf(wv[3][nn]) << 48);
            int byteoff = (row * 128 + wk0 * 2) ^ (swz << 4);
            *reinterpret_cast<unsigned long long*>(reinterpret_cast<char*>(Ws) + byteoff) = pk;
        }
        __syncthreads();
        #pragma unroll
        for (int kb = 0; kb < 2; ++kb) {
            s16x8 af[4], bfr[2];
            #pragma unroll
            for (int mi = 0; mi < 4; ++mi) {
                int r = wm * 64 + mi * 16 + (lane & 15);
                int swz = (r ^ (r >> 3)) & 7;
                int chunk = ((lane >> 4) + kb * 4) ^ swz;
                af[mi] = *reinterpret_cast<const s16x8*>(&As[r * 64 + chunk * 8]);
            }
            #pragma unroll
            for (int ni = 0; ni < 2; ++ni) {
                int r = wn * 32 + ni * 16 + (lane & 15);
                int swz = (r ^ (r >> 3)) & 7;
                int chunk = ((lane >> 4) + kb * 4) ^ swz;
                bfr[ni] = *reinterpret_cast<const s16x8*>(&Ws[r * 64 + chunk * 8]);
            }
            #pragma unroll
            for (int mi = 0; mi < 4; ++mi)
                #pragma unroll
                for (int ni = 0; ni < 2; ++ni)
                    acc[mi][ni] = __builtin_amdgcn_mfma_f32_16x16x32_bf16(af[mi], bfr[ni], acc[mi][ni], 0, 0, 0);
        }
    }
    #pragma unroll
    for (int mi = 0; mi < 4; ++mi)
        #pragma unroll
        for (int ni = 0; ni < 2; ++ni)
            #pragma unroll
            for (int r = 0; r < 4; ++r) {
                int row = mtile * 128 + wm * 64 + mi * 16 + ((lane >> 4) << 2) + r;
                int col = ntile * 64 + wn * 32 + ni * 16 + (lane & 15);
                qpre[((size_t)sq * B_ + row) * D_ + col] = __float2bfloat16(acc[mi][ni][r]);
            }
}

// ---------------- kernel 5: +b2, LayerNorm over D, transposed write ----------------
__global__ __launch_bounds__(256) void lnout_kernel(
    const __hip_bfloat16* __restrict__ qpre,   // (S*Nq, B, D) bf16
    const float* __restrict__ b2,
    const float* __restrict__ lng,
    const float* __restrict__ lnb,
    float* __restrict__ out)          // (S,B,Nq,D)
{
    const int idx = blockIdx.x;       // sq*B + b
    const int sq = idx >> 8;
    const int b = idx & 255;
    const int tid = threadIdx.x;
    __shared__ float red[8];

    float v[2];
    #pragma unroll
    for (int k = 0; k < 2; ++k) {
        int d = tid + k * 256;
        v[k] = __bfloat162float(qpre[(size_t)idx * D_ + d]) + b2[sq * D_ + d];
    }
    float sum = block_sum256(v[0] + v[1], red);
    float sq2 = block_sum256(v[0] * v[0] + v[1] * v[1], red);
    float mu = sum / D_;
    float var = sq2 / D_ - mu * mu;
    float rinv = rsqrtf(var + 1e-5f);
    const int s = sq >> 2, q = sq & 3;
    #pragma unroll
    for (int k = 0; k < 2; ++k) {
        int d = tid + k * 256;
        float o = (v[k] - mu) * rinv * lng[sq * D_ + d] + lnb[sq * D_ + d];
        out[(((size_t)s * B_ + b) * NQ_ + q) * D_ + d] = o;
    }
}

extern "C" void kernel_launch(void* const* d_in, const int* in_sizes, int n_in,
                              void* d_out, int out_size, void* d_ws, size_t ws_size,
                              hipStream_t stream) {
    const float* ns_tokens   = (const float*)d_in[0];
    const float* seq_tokens  = (const float*)d_in[1];
    const unsigned char* masks = (const unsigned char*)d_in[2];
    const float* seq_stats   = (const float*)d_in[3];
    const float* gin_gamma   = (const float*)d_in[4];
    const float* gin_beta    = (const float*)d_in[5];
    const float* stat_W      = (const float*)d_in[6];
    const float* stat_b      = (const float*)d_in[7];
    const float* stat_ln_g   = (const float*)d_in[8];
    const float* stat_ln_b   = (const float*)d_in[9];
    const float* W1          = (const float*)d_in[10];
    const float* b1          = (const float*)d_in[11];
    const float* W2          = (const float*)d_in[12];
    const float* b2          = (const float*)d_in[13];
    const float* ln_g        = (const float*)d_in[14];
    const float* ln_b        = (const float*)d_in[15];
    float* out = (float*)d_out;

    // ws layout: pooled f32 2 MB | gi2 bf16 6 MB | h bf16 16.8 MB | qpre bf16 4.2 MB
    char* ws = (char*)d_ws;
    float* pooled        = (float*)(ws);
    __hip_bfloat16* gi2  = (__hip_bfloat16*)(ws + 2097152);
    __hip_bfloat16* hbuf = (__hip_bfloat16*)(ws + 2097152 + 6291456);
    __hip_bfloat16* qpre = (__hip_bfloat16*)(ws + 2097152 + 6291456 + 16777216);

    pool_kernel<<<dim3(S_ * B_), dim3(256), 0, stream>>>(seq_tokens, masks, pooled);
    gi_kernel<<<dim3(S_ * B_), dim3(256), 0, stream>>>(ns_tokens, seq_stats, stat_W, stat_b,
                                                       stat_ln_g, stat_ln_b, gin_gamma, gin_beta,
                                                       pooled, gi2);
    gemm1_kernel<<<dim3(64 * S_ * NQ_), dim3(256), 0, stream>>>(gi2, W1, b1, hbuf);
    gemm2_kernel<<<dim3(D_ / 64, B_ / 128, S_ * NQ_), dim3(256), 0, stream>>>(hbuf, W2, qpre);
    lnout_kernel<<<dim3(S_ * NQ_ * B_), dim3(256), 0, stream>>>(qpre, b2, ln_g, ln_b, out);
}

// Round 6
// 273.976 us; speedup vs baseline: 1.5412x; 1.5412x over previous
//
#include <hip/hip_runtime.h>
#include <hip/hip_bf16.h>

#define S_ 4
#define B_ 256
#define L_ 256
#define D_ 512
#define NQ_ 4
#define H_ 2048
#define G_ 3072

typedef __attribute__((ext_vector_type(4))) float f32x4;
typedef __attribute__((ext_vector_type(8))) short s16x8;

__device__ __forceinline__ unsigned short f2bf(float x) {
    __hip_bfloat16 hb = __float2bfloat16(x);
    return reinterpret_cast<unsigned short&>(hb);
}

// block-wide sum for 256-thread blocks; red is __shared__ float[8]
__device__ __forceinline__ float block_sum256(float v, float* red) {
    #pragma unroll
    for (int off = 32; off > 0; off >>= 1) v += __shfl_down(v, off, 64);
    int tid = threadIdx.x;
    int lane = tid & 63, wid = tid >> 6;
    if (lane == 0) red[wid] = v;
    __syncthreads();
    float r = (tid < 4) ? red[tid] : 0.f;
    #pragma unroll
    for (int off = 4; off > 0; off >>= 1) r += __shfl_down(r, off, 64);
    if (tid == 0) red[0] = r;
    __syncthreads();
    float out = red[0];
    __syncthreads();
    return out;
}

// ---------------- kernel 1: masked mean pool over L (r2 exact) ----------------
__global__ __launch_bounds__(256) void pool_kernel(
    const float* __restrict__ seq_tokens,
    const unsigned char* __restrict__ masks_raw,
    float* __restrict__ pooled)                // (S,B,D)
{
    const int sb = blockIdx.x;
    const int tid = threadIdx.x;
    __shared__ float sval[L_];
    __shared__ float scount[4];
    __shared__ f32x4 spart[256];
    __shared__ int is_bool_flag;

    if (tid == 0) is_bool_flag = 0;
    __syncthreads();
    {
        unsigned int w = reinterpret_cast<const unsigned int*>(masks_raw)[tid];
        if (w & 0xFFFFFF00u) is_bool_flag = 1;   // benign race, same value
    }
    __syncthreads();
    const bool is_bool = (is_bool_flag != 0);

    int mval;
    if (is_bool) mval = masks_raw[(size_t)sb * L_ + tid];
    else         mval = reinterpret_cast<const int*>(masks_raw)[(size_t)sb * L_ + tid];
    float valid = mval ? 0.f : 1.f;
    sval[tid] = valid;
    float c = valid;
    #pragma unroll
    for (int off = 32; off > 0; off >>= 1) c += __shfl_down(c, off, 64);
    if ((tid & 63) == 0) scount[tid >> 6] = c;
    __syncthreads();
    const float denom = fmaxf(scount[0] + scount[1] + scount[2] + scount[3], 1.f);

    const float* base = seq_tokens + (size_t)sb * L_ * D_;
    const int cidx = tid & 127;
    const int rg = tid >> 7;
    f32x4 acc = {0.f, 0.f, 0.f, 0.f};
    for (int l = rg; l < L_; l += 2) {
        float vl = sval[l];
        f32x4 v = *reinterpret_cast<const f32x4*>(base + (size_t)l * D_ + cidx * 4);
        acc += v * vl;
    }
    spart[tid] = acc;
    __syncthreads();
    if (tid < 128) {
        f32x4 r = spart[tid] + spart[tid + 128];
        r *= (1.f / denom);
        *reinterpret_cast<f32x4*>(pooled + (size_t)sb * D_ + cidx * 4) = r;
    }
}

// ---------------- kernel 2: stat proj + LN, concat, group LN -> gi (bf16) (r2 exact) ---------
__global__ __launch_bounds__(256) void gi_kernel(
    const float* __restrict__ ns_tokens,    // (B, 2048)
    const float* __restrict__ seq_stats,    // (S,B,6)
    const float* __restrict__ stat_W,       // (S,6,D)
    const float* __restrict__ stat_b,       // (S,D)
    const float* __restrict__ stat_ln_g,
    const float* __restrict__ stat_ln_b,
    const float* __restrict__ gin_gamma,    // (G)
    const float* __restrict__ gin_beta,
    const float* __restrict__ pooled,       // (S,B,D)
    __hip_bfloat16* __restrict__ gi)        // (S,B,G)
{
    const int sb = blockIdx.x;
    const int s = sb >> 8;
    const int b = sb & 255;
    const int tid = threadIdx.x;
    __shared__ float red[8];
    __shared__ float sstat[D_];

    float st[6];
    #pragma unroll
    for (int f = 0; f < 6; ++f) st[f] = seq_stats[(size_t)sb * 6 + f];

    float sp[2];
    #pragma unroll
    for (int k = 0; k < 2; ++k) {
        int d = tid + k * 256;
        float a = stat_b[s * D_ + d];
        #pragma unroll
        for (int f = 0; f < 6; ++f) a += st[f] * stat_W[(s * 6 + f) * D_ + d];
        sp[k] = a;
    }
    float ssum = block_sum256(sp[0] + sp[1], red);
    float ssq  = block_sum256(sp[0] * sp[0] + sp[1] * sp[1], red);
    float mu = ssum / D_;
    float var = ssq / D_ - mu * mu;
    float rinv = rsqrtf(var + 1e-5f);
    #pragma unroll
    for (int k = 0; k < 2; ++k) {
        int d = tid + k * 256;
        sstat[d] = (sp[k] - mu) * rinv * stat_ln_g[s * D_ + d] + stat_ln_b[s * D_ + d];
    }
    __syncthreads();

    float gv[12];
    float gsum = 0.f, gsq = 0.f;
    #pragma unroll
    for (int k = 0; k < 12; ++k) {
        int g = tid + k * 256;
        float v;
        if (g < 2048)       v = ns_tokens[(size_t)b * 2048 + g];
        else if (g < 2560)  v = pooled[(size_t)sb * D_ + (g - 2048)];
        else                v = sstat[g - 2560];
        gv[k] = v;
        gsum += v;
        gsq += v * v;
    }
    gsum = block_sum256(gsum, red);
    gsq  = block_sum256(gsq, red);
    mu = gsum / G_;
    var = gsq / G_ - mu * mu;
    rinv = rsqrtf(var + 1e-5f);
    #pragma unroll
    for (int k = 0; k < 12; ++k) {
        int g = tid + k * 256;
        float o = (gv[k] - mu) * rinv * gin_gamma[g] + gin_beta[g];
        gi[(size_t)sb * G_ + g] = __float2bfloat16(o);
    }
}

// ---------------- kernel 3: GEMM1  h = silu(gi @ W1 + b1) -- r2 structure + XCD swizzle ------
// per (s,q): (256 x 3072) x (3072 x 2048). BM=256 (W1 read once), BN=64, BK=64.
// ONE change vs the 268us baseline: bijective XCD swizzle so each XCD owns one s-slice of gi
// (1.5 MB < 4 MB L2) -> the 0.8 GB of A-staging traffic becomes L2 hits instead of L3 thrash.
// Plus W loads issued before A loads (HBM latency first).
__global__ __launch_bounds__(256) void gemm1_kernel(
    const __hip_bfloat16* __restrict__ gi,
    const float* __restrict__ W1,
    const float* __restrict__ b1,
    __hip_bfloat16* __restrict__ hbuf)      // (S*Nq, B, H)
{
    // 512 blocks; XCD x owns wg x*64..x*64+63 -> sq = 2x,2x+1 -> one s-slice per XCD
    const int bid = blockIdx.x;
    const int wg = (bid & 7) * 64 + (bid >> 3);
    const int ntile = wg & 31;      // 0..31
    const int sq = wg >> 5;         // 0..15
    const int s = sq >> 2;
    const int tid = threadIdx.x;
    const int lane = tid & 63;
    const int wid = tid >> 6;       // 0..3 (wave m-block)

    __shared__ __align__(16) unsigned short As[256 * 64];
    __shared__ __align__(16) unsigned short Ws[64 * 64];

    const __hip_bfloat16* Ab = gi + (size_t)s * B_ * G_;
    const float* Wb = W1 + (size_t)sq * G_ * H_ + ntile * 64;

    f32x4 acc[4][4];
    #pragma unroll
    for (int i = 0; i < 4; ++i)
        #pragma unroll
        for (int j = 0; j < 4; ++j) acc[i][j] = (f32x4){0.f, 0.f, 0.f, 0.f};

    const int wn0 = (tid & 15) * 4;   // W stage: n block
    const int wk0 = (tid >> 4) * 4;   // W stage: k block

    for (int kt = 0; kt < G_ / 64; ++kt) {
        const int kbase = kt * 64;
        __syncthreads();
        // W loads first: HBM stream, longest latency
        float wv[4][4];
        #pragma unroll
        for (int kk = 0; kk < 4; ++kk) {
            f32x4 t = *reinterpret_cast<const f32x4*>(Wb + (size_t)(kbase + wk0 + kk) * H_ + wn0);
            #pragma unroll
            for (int j = 0; j < 4; ++j) wv[kk][j] = t[j];
        }
        // A stage: 256x64 bf16, swizzled (L2-resident after XCD swizzle)
        #pragma unroll
        for (int i = 0; i < 8; ++i) {
            int slot = i * 256 + tid;
            int row = slot >> 3, cc = slot & 7;
            int swz = (row ^ (row >> 3)) & 7;
            s16x8 v = *reinterpret_cast<const s16x8*>(Ab + (size_t)row * G_ + kbase + cc * 8);
            *reinterpret_cast<s16x8*>(&As[row * 64 + ((cc ^ swz) * 8)]) = v;
        }
        // W pack: f32 -> bf16, transpose to Ws[n][k]
        #pragma unroll
        for (int nn = 0; nn < 4; ++nn) {
            int row = wn0 + nn;
            int swz = (row ^ (row >> 3)) & 7;
            unsigned long long pk =
                (unsigned long long)f2bf(wv[0][nn]) |
                ((unsigned long long)f2bf(wv[1][nn]) << 16) |
                ((unsigned long long)f2bf(wv[2][nn]) << 32) |
                ((unsigned long long)f2bf(wv[3][nn]) << 48);
            int byteoff = (row * 128 + wk0 * 2) ^ (swz << 4);
            *reinterpret_cast<unsigned long long*>(reinterpret_cast<char*>(Ws) + byteoff) = pk;
        }
        __syncthreads();
        #pragma unroll
        for (int kb = 0; kb < 2; ++kb) {
            s16x8 af[4], bfr[4];
            #pragma unroll
            for (int mi = 0; mi < 4; ++mi) {
                int r = wid * 64 + mi * 16 + (lane & 15);
                int swz = (r ^ (r >> 3)) & 7;
                int chunk = ((lane >> 4) + kb * 4) ^ swz;
                af[mi] = *reinterpret_cast<const s16x8*>(&As[r * 64 + chunk * 8]);
            }
            #pragma unroll
            for (int ni = 0; ni < 4; ++ni) {
                int r = ni * 16 + (lane & 15);
                int swz = (r ^ (r >> 3)) & 7;
                int chunk = ((lane >> 4) + kb * 4) ^ swz;
                bfr[ni] = *reinterpret_cast<const s16x8*>(&Ws[r * 64 + chunk * 8]);
            }
            #pragma unroll
            for (int mi = 0; mi < 4; ++mi)
                #pragma unroll
                for (int ni = 0; ni < 4; ++ni)
                    acc[mi][ni] = __builtin_amdgcn_mfma_f32_16x16x32_bf16(af[mi], bfr[ni], acc[mi][ni], 0, 0, 0);
        }
    }
    // epilogue: + b1, silu, bf16 store
    const float* b1p = b1 + (size_t)sq * H_ + ntile * 64;
    __hip_bfloat16* hp = hbuf + (size_t)sq * B_ * H_;
    #pragma unroll
    for (int mi = 0; mi < 4; ++mi)
        #pragma unroll
        for (int ni = 0; ni < 4; ++ni)
            #pragma unroll
            for (int r = 0; r < 4; ++r) {
                int row = wid * 64 + mi * 16 + ((lane >> 4) << 2) + r;
                int coll = ni * 16 + (lane & 15);
                float x = acc[mi][ni][r] + b1p[coll];
                float sg = 1.f / (1.f + __expf(-x));
                hp[(size_t)row * H_ + ntile * 64 + coll] = __float2bfloat16(x * sg);
            }
}

// ---------------- kernel 4: GEMM2  qpre = h @ W2 (bf16 out, XCD swizzle) ----------------
// per (s,q): (256 x 2048) x (2048 x 512). BM=128, BN=64, BK=64, 4 waves (2x2), wave = 64x32.
__global__ __launch_bounds__(256) void gemm2_kernel(
    const __hip_bfloat16* __restrict__ hbuf,
    const float* __restrict__ W2,
    __hip_bfloat16* __restrict__ qpre)      // (S*Nq, B, D)
{
    // 256 blocks; XCD x owns wg x*32..x*32+31 -> sq = 2x,2x+1 -> h slice 2 MB per XCD
    const int bid = blockIdx.x;
    const int wg = (bid & 7) * 32 + (bid >> 3);
    const int ntile = wg & 7;           // 0..7
    const int mtile = (wg >> 3) & 1;    // 0..1
    const int sq = wg >> 4;             // 0..15
    const int tid = threadIdx.x;
    const int lane = tid & 63;
    const int wid = tid >> 6;
    const int wm = wid >> 1, wn = wid & 1;

    __shared__ __align__(16) unsigned short As[128 * 64];
    __shared__ __align__(16) unsigned short Ws[64 * 64];

    const __hip_bfloat16* Ab = hbuf + ((size_t)sq * B_ + mtile * 128) * H_;
    const float* Wb = W2 + (size_t)sq * H_ * D_ + ntile * 64;

    f32x4 acc[4][2];
    #pragma unroll
    for (int i = 0; i < 4; ++i)
        #pragma unroll
        for (int j = 0; j < 2; ++j) acc[i][j] = (f32x4){0.f, 0.f, 0.f, 0.f};

    const int wn0 = (tid & 15) * 4;
    const int wk0 = (tid >> 4) * 4;

    for (int kt = 0; kt < H_ / 64; ++kt) {
        const int kbase = kt * 64;
        __syncthreads();
        float wv[4][4];
        #pragma unroll
        for (int kk = 0; kk < 4; ++kk) {
            f32x4 t = *reinterpret_cast<const f32x4*>(Wb + (size_t)(kbase + wk0 + kk) * D_ + wn0);
            #pragma unroll
            for (int j = 0; j < 4; ++j) wv[kk][j] = t[j];
        }
        #pragma unroll
        for (int i = 0; i < 4; ++i) {
            int slot = i * 256 + tid;
            int row = slot >> 3, cc = slot & 7;
            int swz = (row ^ (row >> 3)) & 7;
            s16x8 v = *reinterpret_cast<const s16x8*>(Ab + (size_t)row * H_ + kbase + cc * 8);
            *reinterpret_cast<s16x8*>(&As[row * 64 + ((cc ^ swz) * 8)]) = v;
        }
        #pragma unroll
        for (int nn = 0; nn < 4; ++nn) {
            int row = wn0 + nn;
            int swz = (row ^ (row >> 3)) & 7;
            unsigned long long pk =
                (unsigned long long)f2bf(wv[0][nn]) |
                ((unsigned long long)f2bf(wv[1][nn]) << 16) |
                ((unsigned long long)f2bf(wv[2][nn]) << 32) |
                ((unsigned long long)f2bf(wv[3][nn]) << 48);
            int byteoff = (row * 128 + wk0 * 2) ^ (swz << 4);
            *reinterpret_cast<unsigned long long*>(reinterpret_cast<char*>(Ws) + byteoff) = pk;
        }
        __syncthreads();
        #pragma unroll
        for (int kb = 0; kb < 2; ++kb) {
            s16x8 af[4], bfr[2];
            #pragma unroll
            for (int mi = 0; mi < 4; ++mi) {
                int r = wm * 64 + mi * 16 + (lane & 15);
                int swz = (r ^ (r >> 3)) & 7;
                int chunk = ((lane >> 4) + kb * 4) ^ swz;
                af[mi] = *reinterpret_cast<const s16x8*>(&As[r * 64 + chunk * 8]);
            }
            #pragma unroll
            for (int ni = 0; ni < 2; ++ni) {
                int r = wn * 32 + ni * 16 + (lane & 15);
                int swz = (r ^ (r >> 3)) & 7;
                int chunk = ((lane >> 4) + kb * 4) ^ swz;
                bfr[ni] = *reinterpret_cast<const s16x8*>(&Ws[r * 64 + chunk * 8]);
            }
            #pragma unroll
            for (int mi = 0; mi < 4; ++mi)
                #pragma unroll
                for (int ni = 0; ni < 2; ++ni)
                    acc[mi][ni] = __builtin_amdgcn_mfma_f32_16x16x32_bf16(af[mi], bfr[ni], acc[mi][ni], 0, 0, 0);
        }
    }
    #pragma unroll
    for (int mi = 0; mi < 4; ++mi)
        #pragma unroll
        for (int ni = 0; ni < 2; ++ni)
            #pragma unroll
            for (int r = 0; r < 4; ++r) {
                int row = mtile * 128 + wm * 64 + mi * 16 + ((lane >> 4) << 2) + r;
                int col = ntile * 64 + wn * 32 + ni * 16 + (lane & 15);
                qpre[((size_t)sq * B_ + row) * D_ + col] = __float2bfloat16(acc[mi][ni][r]);
            }
}

// ---------------- kernel 5: +b2, LayerNorm over D, transposed write ----------------
__global__ __launch_bounds__(256) void lnout_kernel(
    const __hip_bfloat16* __restrict__ qpre,   // (S*Nq, B, D) bf16
    const float* __restrict__ b2,
    const float* __restrict__ lng,
    const float* __restrict__ lnb,
    float* __restrict__ out)          // (S,B,Nq,D)
{
    const int idx = blockIdx.x;       // sq*B + b
    const int sq = idx >> 8;
    const int b = idx & 255;
    const int tid = threadIdx.x;
    __shared__ float red[8];

    float v[2];
    #pragma unroll
    for (int k = 0; k < 2; ++k) {
        int d = tid + k * 256;
        v[k] = __bfloat162float(qpre[(size_t)idx * D_ + d]) + b2[sq * D_ + d];
    }
    float sum = block_sum256(v[0] + v[1], red);
    float sq2 = block_sum256(v[0] * v[0] + v[1] * v[1], red);
    float mu = sum / D_;
    float var = sq2 / D_ - mu * mu;
    float rinv = rsqrtf(var + 1e-5f);
    const int s = sq >> 2, q = sq & 3;
    #pragma unroll
    for (int k = 0; k < 2; ++k) {
        int d = tid + k * 256;
        float o = (v[k] - mu) * rinv * lng[sq * D_ + d] + lnb[sq * D_ + d];
        out[(((size_t)s * B_ + b) * NQ_ + q) * D_ + d] = o;
    }
}

extern "C" void kernel_launch(void* const* d_in, const int* in_sizes, int n_in,
                              void* d_out, int out_size, void* d_ws, size_t ws_size,
                              hipStream_t stream) {
    const float* ns_tokens   = (const float*)d_in[0];
    const float* seq_tokens  = (const float*)d_in[1];
    const unsigned char* masks = (const unsigned char*)d_in[2];
    const float* seq_stats   = (const float*)d_in[3];
    const float* gin_gamma   = (const float*)d_in[4];
    const float* gin_beta    = (const float*)d_in[5];
    const float* stat_W      = (const float*)d_in[6];
    const float* stat_b      = (const float*)d_in[7];
    const float* stat_ln_g   = (const float*)d_in[8];
    const float* stat_ln_b   = (const float*)d_in[9];
    const float* W1          = (const float*)d_in[10];
    const float* b1          = (const float*)d_in[11];
    const float* W2          = (const float*)d_in[12];
    const float* b2          = (const float*)d_in[13];
    const float* ln_g        = (const float*)d_in[14];
    const float* ln_b        = (const float*)d_in[15];
    float* out = (float*)d_out;

    // ws layout: pooled f32 2 MB | gi bf16 6 MB | h bf16 16.8 MB | qpre bf16 4.2 MB
    char* ws = (char*)d_ws;
    float* pooled        = (float*)(ws);
    __hip_bfloat16* gi   = (__hip_bfloat16*)(ws + 2097152);
    __hip_bfloat16* hbuf = (__hip_bfloat16*)(ws + 2097152 + 6291456);
    __hip_bfloat16* qpre = (__hip_bfloat16*)(ws + 2097152 + 6291456 + 16777216);

    pool_kernel<<<dim3(S_ * B_), dim3(256), 0, stream>>>(seq_tokens, masks, pooled);
    gi_kernel<<<dim3(S_ * B_), dim3(256), 0, stream>>>(ns_tokens, seq_stats, stat_W, stat_b,
                                                       stat_ln_g, stat_ln_b, gin_gamma, gin_beta,
                                                       pooled, gi);
    gemm1_kernel<<<dim3(32 * S_ * NQ_), dim3(256), 0, stream>>>(gi, W1, b1, hbuf);
    gemm2_kernel<<<dim3(2 * D_ / 64 * S_ * NQ_), dim3(256), 0, stream>>>(hbuf, W2, qpre);
    lnout_kernel<<<dim3(S_ * NQ_ * B_), dim3(256), 0, stream>>>(qpre, b2, ln_g, ln_b, out);
}

// Round 7
// 268.796 us; speedup vs baseline: 1.5709x; 1.0193x over previous
//
#include <hip/hip_runtime.h>
#include <hip/hip_bf16.h>

#define S_ 4
#define B_ 256
#define L_ 256
#define D_ 512
#define NQ_ 4
#define H_ 2048
#define G_ 3072

typedef __attribute__((ext_vector_type(4))) float f32x4;
typedef __attribute__((ext_vector_type(8))) short s16x8;

__device__ __forceinline__ unsigned short f2bf(float x) {
    __hip_bfloat16 hb = __float2bfloat16(x);
    return reinterpret_cast<unsigned short&>(hb);
}

// async global->LDS, 16B per lane, LDS dest = wave-uniform base + lane*16
__device__ __forceinline__ void gll16(const void* g, void* l) {
    __builtin_amdgcn_global_load_lds(
        (const __attribute__((address_space(1))) unsigned int*)g,
        (__attribute__((address_space(3))) unsigned int*)l, 16, 0, 0);
}

// block-wide sum for 256-thread blocks; red is __shared__ float[8]
__device__ __forceinline__ float block_sum256(float v, float* red) {
    #pragma unroll
    for (int off = 32; off > 0; off >>= 1) v += __shfl_down(v, off, 64);
    int tid = threadIdx.x;
    int lane = tid & 63, wid = tid >> 6;
    if (lane == 0) red[wid] = v;
    __syncthreads();
    float r = (tid < 4) ? red[tid] : 0.f;
    #pragma unroll
    for (int off = 4; off > 0; off >>= 1) r += __shfl_down(r, off, 64);
    if (tid == 0) red[0] = r;
    __syncthreads();
    float out = red[0];
    __syncthreads();
    return out;
}

// ---------------- kernel 1: masked mean pool over L (r2 exact) ----------------
__global__ __launch_bounds__(256) void pool_kernel(
    const float* __restrict__ seq_tokens,
    const unsigned char* __restrict__ masks_raw,
    float* __restrict__ pooled)                // (S,B,D)
{
    const int sb = blockIdx.x;
    const int tid = threadIdx.x;
    __shared__ float sval[L_];
    __shared__ float scount[4];
    __shared__ f32x4 spart[256];
    __shared__ int is_bool_flag;

    if (tid == 0) is_bool_flag = 0;
    __syncthreads();
    {
        unsigned int w = reinterpret_cast<const unsigned int*>(masks_raw)[tid];
        if (w & 0xFFFFFF00u) is_bool_flag = 1;   // benign race, same value
    }
    __syncthreads();
    const bool is_bool = (is_bool_flag != 0);

    int mval;
    if (is_bool) mval = masks_raw[(size_t)sb * L_ + tid];
    else         mval = reinterpret_cast<const int*>(masks_raw)[(size_t)sb * L_ + tid];
    float valid = mval ? 0.f : 1.f;
    sval[tid] = valid;
    float c = valid;
    #pragma unroll
    for (int off = 32; off > 0; off >>= 1) c += __shfl_down(c, off, 64);
    if ((tid & 63) == 0) scount[tid >> 6] = c;
    __syncthreads();
    const float denom = fmaxf(scount[0] + scount[1] + scount[2] + scount[3], 1.f);

    const float* base = seq_tokens + (size_t)sb * L_ * D_;
    const int cidx = tid & 127;
    const int rg = tid >> 7;
    f32x4 acc = {0.f, 0.f, 0.f, 0.f};
    for (int l = rg; l < L_; l += 2) {
        float vl = sval[l];
        f32x4 v = *reinterpret_cast<const f32x4*>(base + (size_t)l * D_ + cidx * 4);
        acc += v * vl;
    }
    spart[tid] = acc;
    __syncthreads();
    if (tid < 128) {
        f32x4 r = spart[tid] + spart[tid + 128];
        r *= (1.f / denom);
        *reinterpret_cast<f32x4*>(pooled + (size_t)sb * D_ + cidx * 4) = r;
    }
}

// ---------------- kernel 2: stat proj + LN, concat, group LN -> gi (bf16) (r2 exact) ---------
__global__ __launch_bounds__(256) void gi_kernel(
    const float* __restrict__ ns_tokens,    // (B, 2048)
    const float* __restrict__ seq_stats,    // (S,B,6)
    const float* __restrict__ stat_W,       // (S,6,D)
    const float* __restrict__ stat_b,       // (S,D)
    const float* __restrict__ stat_ln_g,
    const float* __restrict__ stat_ln_b,
    const float* __restrict__ gin_gamma,    // (G)
    const float* __restrict__ gin_beta,
    const float* __restrict__ pooled,       // (S,B,D)
    __hip_bfloat16* __restrict__ gi)        // (S,B,G)
{
    const int sb = blockIdx.x;
    const int s = sb >> 8;
    const int b = sb & 255;
    const int tid = threadIdx.x;
    __shared__ float red[8];
    __shared__ float sstat[D_];

    float st[6];
    #pragma unroll
    for (int f = 0; f < 6; ++f) st[f] = seq_stats[(size_t)sb * 6 + f];

    float sp[2];
    #pragma unroll
    for (int k = 0; k < 2; ++k) {
        int d = tid + k * 256;
        float a = stat_b[s * D_ + d];
        #pragma unroll
        for (int f = 0; f < 6; ++f) a += st[f] * stat_W[(s * 6 + f) * D_ + d];
        sp[k] = a;
    }
    float ssum = block_sum256(sp[0] + sp[1], red);
    float ssq  = block_sum256(sp[0] * sp[0] + sp[1] * sp[1], red);
    float mu = ssum / D_;
    float var = ssq / D_ - mu * mu;
    float rinv = rsqrtf(var + 1e-5f);
    #pragma unroll
    for (int k = 0; k < 2; ++k) {
        int d = tid + k * 256;
        sstat[d] = (sp[k] - mu) * rinv * stat_ln_g[s * D_ + d] + stat_ln_b[s * D_ + d];
    }
    __syncthreads();

    float gv[12];
    float gsum = 0.f, gsq = 0.f;
    #pragma unroll
    for (int k = 0; k < 12; ++k) {
        int g = tid + k * 256;
        float v;
        if (g < 2048)       v = ns_tokens[(size_t)b * 2048 + g];
        else if (g < 2560)  v = pooled[(size_t)sb * D_ + (g - 2048)];
        else                v = sstat[g - 2560];
        gv[k] = v;
        gsum += v;
        gsq += v * v;
    }
    gsum = block_sum256(gsum, red);
    gsq  = block_sum256(gsq, red);
    mu = gsum / G_;
    var = gsq / G_ - mu * mu;
    rinv = rsqrtf(var + 1e-5f);
    #pragma unroll
    for (int k = 0; k < 12; ++k) {
        int g = tid + k * 256;
        float o = (gv[k] - mu) * rinv * gin_gamma[g] + gin_beta[g];
        gi[(size_t)sb * G_ + g] = __float2bfloat16(o);
    }
}

// ---------------- kernel 3: GEMM1 -- counted-vmcnt pipeline (T3/T4), never drain ----------
// per (s,q): (256 x 3072) x (3072 x 2048). BM=256 (W1 read once), BN=64, BK=64.
// Full dbuf (As 2x32KB, Ws 2x8KB = 80KB). ONE raw s_barrier per K-step; vmcnt never hits 0:
//   issue W(kt+1)->regs, 8x gll A(kt+1)->As[nxt]            (12 VMEM ops)
//   s_waitcnt vmcnt(12) + sched_barrier                     (A(kt) resident; 12 newer in flight)
//   MFMA on As[cur]/Ws[cur]                                 (wave reads only rows it staged)
//   pack W(kt+1)->Ws[nxt]                                   (auto vmcnt(8): glls stay in flight)
//   s_waitcnt lgkmcnt(0); s_barrier                         (ds_writes visible; no vm drain)
__global__ __launch_bounds__(256) void gemm1_kernel(
    const __hip_bfloat16* __restrict__ gi,
    const float* __restrict__ W1,
    const float* __restrict__ b1,
    __hip_bfloat16* __restrict__ hbuf)      // (S*Nq, B, H)
{
    // bijective XCD swizzle: 512 blocks, 64/XCD -> each XCD owns one s-slice of gi
    const int bid = blockIdx.x;
    const int wg = (bid & 7) * 64 + (bid >> 3);
    const int ntile = wg & 31;      // 0..31
    const int sq = wg >> 5;         // 0..15
    const int s = sq >> 2;
    const int tid = threadIdx.x;
    const int lane = tid & 63;
    const int wid = tid >> 6;       // 0..3 (wave m-block)

    __shared__ __align__(16) unsigned short As[2][256 * 64];
    __shared__ __align__(16) unsigned short Ws[2][64 * 64];

    const char* Ag = reinterpret_cast<const char*>(gi + (size_t)s * B_ * G_);
    const float* Wb = W1 + (size_t)sq * G_ * H_ + ntile * 64;

    f32x4 acc[4][4];
    #pragma unroll
    for (int i = 0; i < 4; ++i)
        #pragma unroll
        for (int j = 0; j < 4; ++j) acc[i][j] = (f32x4){0.f, 0.f, 0.f, 0.f};

    // A gll source byte offsets (kt-invariant): dest row = wid*64 + i*8 + (lane>>3),
    // source chunk = (lane&7) ^ swz(row), swz(row) = ((lane>>3) ^ i) & 7
    unsigned aoff[8];
    #pragma unroll
    for (int i = 0; i < 8; ++i) {
        int row = wid * 64 + i * 8 + (lane >> 3);
        int swz = ((lane >> 3) ^ i) & 7;
        aoff[i] = (unsigned)row * (G_ * 2) + (((lane & 7) ^ swz) * 16);
    }

    // W stage constants: 64k x 64n f32, 16 floats/thread (4k x 4n)
    const int wn0 = (tid & 15) * 4;
    const int wk0 = (tid >> 4) * 4;
    unsigned offW[4];
    #pragma unroll
    for (int nn = 0; nn < 4; ++nn) {
        int row = wn0 + nn;
        int swz = (row ^ (row >> 3)) & 7;
        offW[nn] = (unsigned)((row * 128 + wk0 * 2) ^ (swz << 4));
    }

    // LDS read byte offsets (kt-invariant)
    unsigned offA[2][4], offB[2][4];
    #pragma unroll
    for (int kb = 0; kb < 2; ++kb) {
        #pragma unroll
        for (int mi = 0; mi < 4; ++mi) {
            int r = wid * 64 + mi * 16 + (lane & 15);
            int swz = (r ^ (r >> 3)) & 7;
            offA[kb][mi] = r * 128 + ((((lane >> 4) + kb * 4) ^ swz) * 16);
        }
        #pragma unroll
        for (int ni = 0; ni < 4; ++ni) {
            int r = ni * 16 + (lane & 15);
            int swz = (r ^ (r >> 3)) & 7;
            offB[kb][ni] = r * 128 + ((((lane >> 4) + kb * 4) ^ swz) * 16);
        }
    }

    // ---- prologue: stage A(0) via gll, load+pack W(0) -> Ws[0]
    {
        char* dst = reinterpret_cast<char*>(&As[0][0]);
        #pragma unroll
        for (int i = 0; i < 8; ++i)
            gll16(Ag + aoff[i], dst + (wid * 64 + i * 8) * 128);
        f32x4 w0[4];
        #pragma unroll
        for (int kk = 0; kk < 4; ++kk)
            w0[kk] = *reinterpret_cast<const f32x4*>(Wb + (size_t)(wk0 + kk) * H_ + wn0);
        #pragma unroll
        for (int nn = 0; nn < 4; ++nn) {
            unsigned long long pk =
                (unsigned long long)f2bf(w0[0][nn]) |
                ((unsigned long long)f2bf(w0[1][nn]) << 16) |
                ((unsigned long long)f2bf(w0[2][nn]) << 32) |
                ((unsigned long long)f2bf(w0[3][nn]) << 48);
            *reinterpret_cast<unsigned long long*>(reinterpret_cast<char*>(&Ws[0][0]) + offW[nn]) = pk;
        }
        asm volatile("s_waitcnt lgkmcnt(0)" ::: "memory");
        __builtin_amdgcn_s_barrier();
        // A(0) gll completion is enforced by iter 0's vmcnt(12)
    }

    // ---- main loop: 48 K-steps, one barrier each, vmcnt never drained
    for (int kt = 0; kt < G_ / 64; ++kt) {
        const int cur = kt & 1, nxt = cur ^ 1;
        const int kn = (kt < G_ / 64 - 1) ? kt + 1 : G_ / 64 - 1;  // clamp: uniform 12 ops/iter

        // [1] W(kn) -> regs (oldest of this iter's 12)
        f32x4 wreg[4];
        {
            const float* wp = Wb + (size_t)(kn * 64 + wk0) * H_ + wn0;
            #pragma unroll
            for (int kk = 0; kk < 4; ++kk)
                wreg[kk] = *reinterpret_cast<const f32x4*>(wp + (size_t)kk * H_);
        }
        // [2] gll A(kn) -> As[nxt]
        {
            char* dst = reinterpret_cast<char*>(&As[nxt][0]);
            const unsigned kbyte = (unsigned)kn * 128;
            #pragma unroll
            for (int i = 0; i < 8; ++i)
                gll16(Ag + (aoff[i] + kbyte), dst + (wid * 64 + i * 8) * 128);
        }
        // [3] A(kt) resident: all ops older than this iter's 12 have retired
        asm volatile("s_waitcnt vmcnt(12)" ::: "memory");
        __builtin_amdgcn_sched_barrier(0);

        // [4] MFMA on As[cur], Ws[cur]
        const char* Al = reinterpret_cast<const char*>(&As[cur][0]);
        const char* Wl = reinterpret_cast<const char*>(&Ws[cur][0]);
        #pragma unroll
        for (int kb = 0; kb < 2; ++kb) {
            s16x8 af[4], bfr[4];
            #pragma unroll
            for (int mi = 0; mi < 4; ++mi)
                af[mi] = *reinterpret_cast<const s16x8*>(Al + offA[kb][mi]);
            #pragma unroll
            for (int ni = 0; ni < 4; ++ni)
                bfr[ni] = *reinterpret_cast<const s16x8*>(Wl + offB[kb][ni]);
            #pragma unroll
            for (int mi = 0; mi < 4; ++mi)
                #pragma unroll
                for (int ni = 0; ni < 4; ++ni)
                    acc[mi][ni] = __builtin_amdgcn_mfma_f32_16x16x32_bf16(af[mi], bfr[ni], acc[mi][ni], 0, 0, 0);
        }

        // [5] pack W(kn) -> Ws[nxt] (compiler auto-waits the 4 W loads: vmcnt(8), glls in flight)
        #pragma unroll
        for (int nn = 0; nn < 4; ++nn) {
            unsigned long long pk =
                (unsigned long long)f2bf(wreg[0][nn]) |
                ((unsigned long long)f2bf(wreg[1][nn]) << 16) |
                ((unsigned long long)f2bf(wreg[2][nn]) << 32) |
                ((unsigned long long)f2bf(wreg[3][nn]) << 48);
            *reinterpret_cast<unsigned long long*>(reinterpret_cast<char*>(&Ws[nxt][0]) + offW[nn]) = pk;
        }
        // [6] ds_writes visible to all waves; NO vmcnt drain
        asm volatile("s_waitcnt lgkmcnt(0)" ::: "memory");
        __builtin_amdgcn_s_barrier();
    }

    // ---- epilogue: + b1, silu, bf16 store
    const float* b1p = b1 + (size_t)sq * H_ + ntile * 64;
    __hip_bfloat16* hp = hbuf + (size_t)sq * B_ * H_;
    #pragma unroll
    for (int mi = 0; mi < 4; ++mi)
        #pragma unroll
        for (int ni = 0; ni < 4; ++ni)
            #pragma unroll
            for (int r = 0; r < 4; ++r) {
                int row = wid * 64 + mi * 16 + ((lane >> 4) << 2) + r;
                int coll = ni * 16 + (lane & 15);
                float x = acc[mi][ni][r] + b1p[coll];
                float sg = 1.f / (1.f + __expf(-x));
                hp[(size_t)row * H_ + ntile * 64 + coll] = __float2bfloat16(x * sg);
            }
}

// ---------------- kernel 4: GEMM2  qpre = h @ W2 (bf16 out, XCD swizzle) ----------------
__global__ __launch_bounds__(256) void gemm2_kernel(
    const __hip_bfloat16* __restrict__ hbuf,
    const float* __restrict__ W2,
    __hip_bfloat16* __restrict__ qpre)      // (S*Nq, B, D)
{
    const int bid = blockIdx.x;
    const int wg = (bid & 7) * 32 + (bid >> 3);
    const int ntile = wg & 7;           // 0..7
    const int mtile = (wg >> 3) & 1;    // 0..1
    const int sq = wg >> 4;             // 0..15
    const int tid = threadIdx.x;
    const int lane = tid & 63;
    const int wid = tid >> 6;
    const int wm = wid >> 1, wn = wid & 1;

    __shared__ __align__(16) unsigned short As[128 * 64];
    __shared__ __align__(16) unsigned short Ws[64 * 64];

    const __hip_bfloat16* Ab = hbuf + ((size_t)sq * B_ + mtile * 128) * H_;
    const float* Wb = W2 + (size_t)sq * H_ * D_ + ntile * 64;

    f32x4 acc[4][2];
    #pragma unroll
    for (int i = 0; i < 4; ++i)
        #pragma unroll
        for (int j = 0; j < 2; ++j) acc[i][j] = (f32x4){0.f, 0.f, 0.f, 0.f};

    const int wn0 = (tid & 15) * 4;
    const int wk0 = (tid >> 4) * 4;

    for (int kt = 0; kt < H_ / 64; ++kt) {
        const int kbase = kt * 64;
        __syncthreads();
        float wv[4][4];
        #pragma unroll
        for (int kk = 0; kk < 4; ++kk) {
            f32x4 t = *reinterpret_cast<const f32x4*>(Wb + (size_t)(kbase + wk0 + kk) * D_ + wn0);
            #pragma unroll
            for (int j = 0; j < 4; ++j) wv[kk][j] = t[j];
        }
        #pragma unroll
        for (int i = 0; i < 4; ++i) {
            int slot = i * 256 + tid;
            int row = slot >> 3, cc = slot & 7;
            int swz = (row ^ (row >> 3)) & 7;
            s16x8 v = *reinterpret_cast<const s16x8*>(Ab + (size_t)row * H_ + kbase + cc * 8);
            *reinterpret_cast<s16x8*>(&As[row * 64 + ((cc ^ swz) * 8)]) = v;
        }
        #pragma unroll
        for (int nn = 0; nn < 4; ++nn) {
            int row = wn0 + nn;
            int swz = (row ^ (row >> 3)) & 7;
            unsigned long long pk =
                (unsigned long long)f2bf(wv[0][nn]) |
                ((unsigned long long)f2bf(wv[1][nn]) << 16) |
                ((unsigned long long)f2bf(wv[2][nn]) << 32) |
                ((unsigned long long)f2bf(wv[3][nn]) << 48);
            int byteoff = (row * 128 + wk0 * 2) ^ (swz << 4);
            *reinterpret_cast<unsigned long long*>(reinterpret_cast<char*>(Ws) + byteoff) = pk;
        }
        __syncthreads();
        #pragma unroll
        for (int kb = 0; kb < 2; ++kb) {
            s16x8 af[4], bfr[2];
            #pragma unroll
            for (int mi = 0; mi < 4; ++mi) {
                int r = wm * 64 + mi * 16 + (lane & 15);
                int swz = (r ^ (r >> 3)) & 7;
                int chunk = ((lane >> 4) + kb * 4) ^ swz;
                af[mi] = *reinterpret_cast<const s16x8*>(&As[r * 64 + chunk * 8]);
            }
            #pragma unroll
            for (int ni = 0; ni < 2; ++ni) {
                int r = wn * 32 + ni * 16 + (lane & 15);
                int swz = (r ^ (r >> 3)) & 7;
                int chunk = ((lane >> 4) + kb * 4) ^ swz;
                bfr[ni] = *reinterpret_cast<const s16x8*>(&Ws[r * 64 + chunk * 8]);
            }
            #pragma unroll
            for (int mi = 0; mi < 4; ++mi)
                #pragma unroll
                for (int ni = 0; ni < 2; ++ni)
                    acc[mi][ni] = __builtin_amdgcn_mfma_f32_16x16x32_bf16(af[mi], bfr[ni], acc[mi][ni], 0, 0, 0);
        }
    }
    #pragma unroll
    for (int mi = 0; mi < 4; ++mi)
        #pragma unroll
        for (int ni = 0; ni < 2; ++ni)
            #pragma unroll
            for (int r = 0; r < 4; ++r) {
                int row = mtile * 128 + wm * 64 + mi * 16 + ((lane >> 4) << 2) + r;
                int col = ntile * 64 + wn * 32 + ni * 16 + (lane & 15);
                qpre[((size_t)sq * B_ + row) * D_ + col] = __float2bfloat16(acc[mi][ni][r]);
            }
}

// ---------------- kernel 5: +b2, LayerNorm over D, transposed write ----------------
__global__ __launch_bounds__(256) void lnout_kernel(
    const __hip_bfloat16* __restrict__ qpre,   // (S*Nq, B, D) bf16
    const float* __restrict__ b2,
    const float* __restrict__ lng,
    const float* __restrict__ lnb,
    float* __restrict__ out)          // (S,B,Nq,D)
{
    const int idx = blockIdx.x;       // sq*B + b
    const int sq = idx >> 8;
    const int b = idx & 255;
    const int tid = threadIdx.x;
    __shared__ float red[8];

    float v[2];
    #pragma unroll
    for (int k = 0; k < 2; ++k) {
        int d = tid + k * 256;
        v[k] = __bfloat162float(qpre[(size_t)idx * D_ + d]) + b2[sq * D_ + d];
    }
    float sum = block_sum256(v[0] + v[1], red);
    float sq2 = block_sum256(v[0] * v[0] + v[1] * v[1], red);
    float mu = sum / D_;
    float var = sq2 / D_ - mu * mu;
    float rinv = rsqrtf(var + 1e-5f);
    const int s = sq >> 2, q = sq & 3;
    #pragma unroll
    for (int k = 0; k < 2; ++k) {
        int d = tid + k * 256;
        float o = (v[k] - mu) * rinv * lng[sq * D_ + d] + lnb[sq * D_ + d];
        out[(((size_t)s * B_ + b) * NQ_ + q) * D_ + d] = o;
    }
}

extern "C" void kernel_launch(void* const* d_in, const int* in_sizes, int n_in,
                              void* d_out, int out_size, void* d_ws, size_t ws_size,
                              hipStream_t stream) {
    const float* ns_tokens   = (const float*)d_in[0];
    const float* seq_tokens  = (const float*)d_in[1];
    const unsigned char* masks = (const unsigned char*)d_in[2];
    const float* seq_stats   = (const float*)d_in[3];
    const float* gin_gamma   = (const float*)d_in[4];
    const float* gin_beta    = (const float*)d_in[5];
    const float* stat_W      = (const float*)d_in[6];
    const float* stat_b      = (const float*)d_in[7];
    const float* stat_ln_g   = (const float*)d_in[8];
    const float* stat_ln_b   = (const float*)d_in[9];
    const float* W1          = (const float*)d_in[10];
    const float* b1          = (const float*)d_in[11];
    const float* W2          = (const float*)d_in[12];
    const float* b2          = (const float*)d_in[13];
    const float* ln_g        = (const float*)d_in[14];
    const float* ln_b        = (const float*)d_in[15];
    float* out = (float*)d_out;

    // ws layout: pooled f32 2 MB | gi bf16 6 MB | h bf16 16.8 MB | qpre bf16 4.2 MB
    char* ws = (char*)d_ws;
    float* pooled        = (float*)(ws);
    __hip_bfloat16* gi   = (__hip_bfloat16*)(ws + 2097152);
    __hip_bfloat16* hbuf = (__hip_bfloat16*)(ws + 2097152 + 6291456);
    __hip_bfloat16* qpre = (__hip_bfloat16*)(ws + 2097152 + 6291456 + 16777216);

    pool_kernel<<<dim3(S_ * B_), dim3(256), 0, stream>>>(seq_tokens, masks, pooled);
    gi_kernel<<<dim3(S_ * B_), dim3(256), 0, stream>>>(ns_tokens, seq_stats, stat_W, stat_b,
                                                       stat_ln_g, stat_ln_b, gin_gamma, gin_beta,
                                                       pooled, gi);
    gemm1_kernel<<<dim3(32 * S_ * NQ_), dim3(256), 0, stream>>>(gi, W1, b1, hbuf);
    gemm2_kernel<<<dim3(2 * D_ / 64 * S_ * NQ_), dim3(256), 0, stream>>>(hbuf, W2, qpre);
    lnout_kernel<<<dim3(S_ * NQ_ * B_), dim3(256), 0, stream>>>(qpre, b2, ln_g, ln_b, out);
}